// Round 7
// baseline (356.537 us; speedup 1.0000x reference)
//
#include <hip/hip_runtime.h>
#include <hip/hip_bf16.h>
#include <cstdint>
#include <cstddef>

// TripletLoss: inputs (8192,128) fp32, targets (8192,) int32, 64 classes.
// out[0] = loss, out[1..] = dist (8192x8192) row-major fp32.
// v8 = v7 (aligned shifted stores, operand-swapped MFMA, lane-local row
// reduce, no A/B staging, 32KB C-LDS, 4 blocks/CU) + XCD-major bn-sweep
// grid swizzle. Evidence: v1-v7 all pin at 2.2-2.95 TB/s raw; v5 (bn-fast,
// all column windows co-resident) had the HIGHEST raw BW but cross-XCD seam
// thrash (amp 1.75); v4/v7 (bm-fast) had clean seams (amp 1.1) but only
// ~1/8 of bn windows in flight -> channel subset -> ~2.2 TB/s. The dist row
// stride (32KB) aliases the channel hash, so a block's fixed 512B column
// window maps to few channels; spreading bn across co-resident blocks is
// required for full channel coverage.
// Swizzle: xcd = id&7, local = id>>3, bm = (local>>6)*8 + xcd, bn = local&63.
//  (a) co-resident blocks span all 64 bn -> all HBM channels active;
//  (b) seam partners (bm,bn),(bm,bn+1) are ADJACENT dispatches on the SAME
//      XCD -> out+1 edge lines merge in L2 (v4-level amplification);
//  (c) XCDs own disjoint 128-row panels -> zero cross-XCD line sharing.

#define NROWS 8192
#define DIMK  128
#define MARGIN 0.3f

typedef __bf16 bf16x8 __attribute__((ext_vector_type(8)));
typedef float  f32x4  __attribute__((ext_vector_type(4)));
typedef float  f32x2  __attribute__((ext_vector_type(2)));
typedef int    i32x4  __attribute__((ext_vector_type(4)));

__device__ __forceinline__ unsigned short f2bf(float f) {
    // round-to-nearest-even fp32 -> bf16
    unsigned u = __float_as_uint(f);
    u += 0x7fffu + ((u >> 16) & 1u);
    return (unsigned short)(u >> 16);
}

// prep: bf16-convert X into LINEAR Xb, row sq-norms from the ROUNDED values,
// init ap/an. grid 2048 x 256 (one wave per row).
__global__ __launch_bounds__(256) void prep_kernel(
    const float* __restrict__ X, unsigned short* __restrict__ Xb,
    float* __restrict__ sq, int* __restrict__ ap, int* __restrict__ an)
{
    const int t = blockIdx.x * 256 + threadIdx.x;
    if (t < NROWS) { ap[t] = 0; an[t] = 0x7f800000; }  // 0.0f / +inf
    const int row  = t >> 6;
    const int lane = t & 63;
    const f32x2 v = *(const f32x2*)(X + (size_t)row * DIMK + lane * 2);
    const unsigned short b0 = f2bf(v[0]);
    const unsigned short b1 = f2bf(v[1]);
    *(unsigned*)(Xb + (size_t)row * DIMK + lane * 2) =
        (unsigned)b0 | ((unsigned)b1 << 16);
    const float f0 = __uint_as_float((unsigned)b0 << 16);
    const float f1 = __uint_as_float((unsigned)b1 << 16);
    float s = f0 * f0 + f1 * f1;
    #pragma unroll
    for (int off = 32; off; off >>= 1) s += __shfl_xor(s, off);
    if (lane == 0) sq[row] = s;
}

// shifted row store: dist base is out+1, so per lane write [4rc-1, 4rc+3)
// (16B aligned) with the missing element pulled from the left neighbor.
// Each aligned 64B sector is fully covered within one instruction.
__device__ __forceinline__ void store_row_shifted(float* drow, f32x4 d4, int rc) {
    const float prev = __shfl_up(d4[3], 1);
    if (rc == 0) {
        drow[0] = d4[0];
        *(f32x2*)(drow + 1) = (f32x2){d4[1], d4[2]};
    } else {
        *(f32x4*)(drow + (rc << 2) - 1) = (f32x4){prev, d4[0], d4[1], d4[2]};
    }
    if (rc == 31)
        drow[127] = d4[3];
}

__global__ __launch_bounds__(256, 4) void dist_kernel(
    const unsigned short* __restrict__ Xb, const float* __restrict__ sq,
    const int* __restrict__ tgt, float* __restrict__ dist,
    int* __restrict__ ap, int* __restrict__ an)
{
    __shared__ __align__(16) char lds[32 * 1024];  // C half-tile f32 64x128

    // ---- XCD-major bn-sweep decode ----
    const int id    = blockIdx.x;
    const int xcd   = id & 7;
    const int local = id >> 3;
    const int bm    = ((local >> 6) << 3) + xcd;   // XCD owns whole row panels
    const int bn    = local & 63;                  // swept fastest per XCD

    const int t = threadIdx.x;
    const int lane = t & 63, wave = t >> 6;
    const int wm = (wave >> 1) << 6;               // wave's 64-row half
    const int wn = (wave & 1) << 6;                // wave's 64-col half
    const int l15 = lane & 15, quad = lane >> 4;
    const int rbase = bm << 7, cbase = bn << 7;
    const float INF = __int_as_float(0x7f800000);

    // ---- MFMA, operand-swapped: lane's f32x4 = 4 consecutive cols
    // (quad*4+reg) of row l15. Frags direct from global (Xb L2-resident). ----
    f32x4 acc[4][4];
    #pragma unroll
    for (int mi = 0; mi < 4; mi++)
        #pragma unroll
        for (int ni = 0; ni < 4; ni++)
            acc[mi][ni] = (f32x4){0.f, 0.f, 0.f, 0.f};

    const unsigned short* Arow = Xb + (size_t)(rbase + wm + l15) * DIMK;
    const unsigned short* Brow = Xb + (size_t)(cbase + wn + l15) * DIMK;
    #pragma unroll
    for (int ks = 0; ks < 4; ks++) {
        const int kb = ks * 32 + quad * 8;
        bf16x8 af[4], bfr[4];
        #pragma unroll
        for (int mi = 0; mi < 4; mi++)
            af[mi] = *(const bf16x8*)(Arow + mi * 16 * DIMK + kb);
        #pragma unroll
        for (int ni = 0; ni < 4; ni++)
            bfr[ni] = *(const bf16x8*)(Brow + ni * 16 * DIMK + kb);
        #pragma unroll
        for (int mi = 0; mi < 4; mi++)
            #pragma unroll
            for (int ni = 0; ni < 4; ni++)
                acc[mi][ni] = __builtin_amdgcn_mfma_f32_16x16x32_bf16(
                    bfr[ni], af[mi], acc[mi][ni], 0, 0, 0);
    }

    // ---- convert sqd -> d in place + lane-local row reduce ----
    int rg[4]; float sqr[4]; int trg[4];
    #pragma unroll
    for (int mi = 0; mi < 4; mi++) {
        rg[mi]  = rbase + wm + mi * 16 + l15;
        sqr[mi] = sq[rg[mi]];
        trg[mi] = tgt[rg[mi]];
    }
    float apv[4] = {-1.f, -1.f, -1.f, -1.f};
    float anv[4] = {INF, INF, INF, INF};

    #pragma unroll
    for (int ni = 0; ni < 4; ni++) {
        const int c0 = cbase + wn + ni * 16 + quad * 4;   // global col base
        const f32x4 sqc = *(const f32x4*)(sq + c0);
        const i32x4 tc  = *(const i32x4*)(tgt + c0);
        #pragma unroll
        for (int mi = 0; mi < 4; mi++) {
            #pragma unroll
            for (int j = 0; j < 4; j++) {
                const float sqd = sqr[mi] + sqc[j] - 2.0f * acc[mi][ni][j];
                float d = sqd > 0.0f ? sqrtf(sqd) : 0.0f;
                if (rg[mi] == c0 + j) d = 0.0f;           // exact diagonal
                acc[mi][ni][j] = d;
                const bool same = (trg[mi] == tc[j]);
                apv[mi] = fmaxf(apv[mi], same ? d : -1.f);
                anv[mi] = fminf(anv[mi], same ? INF : d);
            }
        }
    }

    // combine the 4 quads holding the same row, one commit per row
    #pragma unroll
    for (int mi = 0; mi < 4; mi++) {
        apv[mi] = fmaxf(apv[mi], __shfl_xor(apv[mi], 16));
        apv[mi] = fmaxf(apv[mi], __shfl_xor(apv[mi], 32));
        anv[mi] = fminf(anv[mi], __shfl_xor(anv[mi], 16));
        anv[mi] = fminf(anv[mi], __shfl_xor(anv[mi], 32));
    }
    if (quad == 0) {
        #pragma unroll
        for (int mi = 0; mi < 4; mi++) {
            atomicMax(ap + rg[mi], __float_as_int(apv[mi]));
            atomicMin(an + rg[mi], __float_as_int(anv[mi]));
        }
    }

    // ---- C tile -> global in two 64-row halves through 32KB LDS ----
    const int rc = t & 31;                 // fixed 16B col-chunk
    const int w  = t >> 5;                 // row subset selector 0..7
    #pragma unroll
    for (int h = 0; h < 2; h++) {
        if (wm == h * 64) {                // the 2 waves owning rows of half h
            #pragma unroll
            for (int mi = 0; mi < 4; mi++) {
                const int rl = mi * 16 + l15;              // local row 0..63
                const int sw = (rl & 7) << 4;
                #pragma unroll
                for (int ni = 0; ni < 4; ni++) {
                    const int cb = (wn + ni * 16 + quad * 4) << 2;  // col byte
                    *(f32x4*)(lds + rl * 512 + (cb ^ sw)) = acc[mi][ni];
                }
            }
        }
        __syncthreads();
        #pragma unroll
        for (int it = 0; it < 8; it++) {
            const int r = it * 8 + w;      // local row 0..63
            const f32x4 d4 = *(const f32x4*)(
                lds + r * 512 + ((rc << 4) ^ ((r & 7) << 4)));
            const int rowg = rbase + h * 64 + r;
            store_row_shifted(dist + (size_t)rowg * NROWS + cbase, d4, rc);
        }
        __syncthreads();
    }
}

__global__ __launch_bounds__(256) void loss_kernel(
    const int* __restrict__ ap, const int* __restrict__ an,
    float* __restrict__ out)
{
    __shared__ float red[4];
    float s = 0.0f;
    for (int i = threadIdx.x; i < NROWS; i += 256) {
        const float v = __int_as_float(ap[i]) - __int_as_float(an[i]) + MARGIN;
        s += v > 0.0f ? v : 0.0f;
    }
    #pragma unroll
    for (int off = 32; off; off >>= 1) s += __shfl_xor(s, off);
    if ((threadIdx.x & 63) == 0) red[threadIdx.x >> 6] = s;
    __syncthreads();
    if (threadIdx.x == 0)
        out[0] = (red[0] + red[1] + red[2] + red[3]) * (1.0f / NROWS);
}

extern "C" void kernel_launch(void* const* d_in, const int* in_sizes, int n_in,
                              void* d_out, int out_size, void* d_ws, size_t ws_size,
                              hipStream_t stream)
{
    const float* X   = (const float*)d_in[0];
    const int*   tgt = (const int*)d_in[1];
    float*       out = (float*)d_out;

    // ws layout: Xb bf16 8192x128 linear (2 MB) | sq (32 KB) | ap | an
    unsigned short* Xb = (unsigned short*)d_ws;
    float* sq = (float*)((char*)d_ws + (size_t)NROWS * DIMK * 2);
    int*   ap = (int*)(sq + NROWS);
    int*   an = ap + NROWS;

    prep_kernel<<<(NROWS * 64) / 256, 256, 0, stream>>>(X, Xb, sq, ap, an);

    dist_kernel<<<4096, 256, 0, stream>>>(Xb, sq, tgt, out + 1, ap, an);

    loss_kernel<<<1, 256, 0, stream>>>(ap, an, out);
}

// Round 8
// 342.554 us; speedup vs baseline: 1.0408x; 1.0408x over previous
//
#include <hip/hip_runtime.h>
#include <hip/hip_bf16.h>
#include <cstdint>
#include <cstddef>

// TripletLoss: inputs (8192,128) fp32, targets (8192,) int32, 64 classes.
// out[0] = loss, out[1..] = dist (8192x8192) row-major fp32.
// v9 = v7 (aligned shifted stores, operand-swapped MFMA, lane-local row
// reduce, direct global frag loads, 32KB C-LDS, 4 blocks/CU, bm-fast grid)
// with the two invariants-of-all-slow-variants removed:
//  (1) ZERO global atomics: v1-v8 all fired ~1M atomicMax/Min at a hot 64KB
//      ap/an region (serialized TCC RMW, shared vmem queues). Now each block
//      plain-stores its per-row partials to a private slot app/anp[bn][row];
//      a tiny reduce kernel folds 64 partials/row and accumulates the loss.
//  (2) NO vmcnt drains at barriers: __syncthreads compiles to
//      s_waitcnt vmcnt(0) lgkmcnt(0); s_barrier, flushing the store pipe
//      2-4x per block. Replaced with lgkmcnt(0)-only raw barriers (LDS
//      ordering is all we need; global stores never block a wave).

#define NROWS 8192
#define DIMK  128
#define MARGIN 0.3f

typedef __bf16 bf16x8 __attribute__((ext_vector_type(8)));
typedef float  f32x4  __attribute__((ext_vector_type(4)));
typedef float  f32x2  __attribute__((ext_vector_type(2)));
typedef int    i32x4  __attribute__((ext_vector_type(4)));

// barrier that orders LDS only -- global stores stay in flight.
#define BAR_LDS() asm volatile("s_waitcnt lgkmcnt(0)\n\ts_barrier" ::: "memory")

__device__ __forceinline__ unsigned short f2bf(float f) {
    // round-to-nearest-even fp32 -> bf16
    unsigned u = __float_as_uint(f);
    u += 0x7fffu + ((u >> 16) & 1u);
    return (unsigned short)(u >> 16);
}

// prep: bf16-convert X into LINEAR Xb, row sq-norms from the ROUNDED values,
// zero the loss accumulator. grid 2048 x 256 (one wave per row).
__global__ __launch_bounds__(256) void prep_kernel(
    const float* __restrict__ X, unsigned short* __restrict__ Xb,
    float* __restrict__ sq, float* __restrict__ out)
{
    if (blockIdx.x == 0 && threadIdx.x == 0) out[0] = 0.0f;
    const int t = blockIdx.x * 256 + threadIdx.x;
    const int row  = t >> 6;
    const int lane = t & 63;
    const f32x2 v = *(const f32x2*)(X + (size_t)row * DIMK + lane * 2);
    const unsigned short b0 = f2bf(v[0]);
    const unsigned short b1 = f2bf(v[1]);
    *(unsigned*)(Xb + (size_t)row * DIMK + lane * 2) =
        (unsigned)b0 | ((unsigned)b1 << 16);
    const float f0 = __uint_as_float((unsigned)b0 << 16);
    const float f1 = __uint_as_float((unsigned)b1 << 16);
    float s = f0 * f0 + f1 * f1;
    #pragma unroll
    for (int off = 32; off; off >>= 1) s += __shfl_xor(s, off);
    if (lane == 0) sq[row] = s;
}

// shifted row store: dist base is out+1, so per lane write [4rc-1, 4rc+3)
// (16B aligned) with the missing element pulled from the left neighbor.
// Each aligned 64B sector is fully covered within one instruction.
__device__ __forceinline__ void store_row_shifted(float* drow, f32x4 d4, int rc) {
    const float prev = __shfl_up(d4[3], 1);
    if (rc == 0) {
        drow[0] = d4[0];
        *(f32x2*)(drow + 1) = (f32x2){d4[1], d4[2]};
    } else {
        *(f32x4*)(drow + (rc << 2) - 1) = (f32x4){prev, d4[0], d4[1], d4[2]};
    }
    if (rc == 31)
        drow[127] = d4[3];
}

__global__ __launch_bounds__(256, 4) void dist_kernel(
    const unsigned short* __restrict__ Xb, const float* __restrict__ sq,
    const int* __restrict__ tgt, float* __restrict__ dist,
    float* __restrict__ app, float* __restrict__ anp)
{
    __shared__ __align__(16) char lds[32 * 1024];  // C half-tile f32 64x128

    const int t = threadIdx.x;
    const int bm = blockIdx.x, bn = blockIdx.y;    // bm FAST (v4/v7 grid)
    const int lane = t & 63, wave = t >> 6;
    const int wm = (wave >> 1) << 6;               // wave's 64-row half
    const int wn = (wave & 1) << 6;                // wave's 64-col half
    const int l15 = lane & 15, quad = lane >> 4;
    const int rbase = bm << 7, cbase = bn << 7;
    const float INF = __int_as_float(0x7f800000);

    // ---- MFMA, operand-swapped: lane's f32x4 = 4 consecutive cols
    // (quad*4+reg) of row l15. Frags direct from global (Xb L2-resident). ----
    f32x4 acc[4][4];
    #pragma unroll
    for (int mi = 0; mi < 4; mi++)
        #pragma unroll
        for (int ni = 0; ni < 4; ni++)
            acc[mi][ni] = (f32x4){0.f, 0.f, 0.f, 0.f};

    const unsigned short* Arow = Xb + (size_t)(rbase + wm + l15) * DIMK;
    const unsigned short* Brow = Xb + (size_t)(cbase + wn + l15) * DIMK;
    #pragma unroll
    for (int ks = 0; ks < 4; ks++) {
        const int kb = ks * 32 + quad * 8;
        bf16x8 af[4], bfr[4];
        #pragma unroll
        for (int mi = 0; mi < 4; mi++)
            af[mi] = *(const bf16x8*)(Arow + mi * 16 * DIMK + kb);
        #pragma unroll
        for (int ni = 0; ni < 4; ni++)
            bfr[ni] = *(const bf16x8*)(Brow + ni * 16 * DIMK + kb);
        #pragma unroll
        for (int mi = 0; mi < 4; mi++)
            #pragma unroll
            for (int ni = 0; ni < 4; ni++)
                acc[mi][ni] = __builtin_amdgcn_mfma_f32_16x16x32_bf16(
                    bfr[ni], af[mi], acc[mi][ni], 0, 0, 0);
    }

    // ---- convert sqd -> d in place + lane-local row reduce ----
    int rg[4]; float sqr[4]; int trg[4];
    #pragma unroll
    for (int mi = 0; mi < 4; mi++) {
        rg[mi]  = rbase + wm + mi * 16 + l15;
        sqr[mi] = sq[rg[mi]];
        trg[mi] = tgt[rg[mi]];
    }
    float apv[4] = {-1.f, -1.f, -1.f, -1.f};
    float anv[4] = {INF, INF, INF, INF};

    #pragma unroll
    for (int ni = 0; ni < 4; ni++) {
        const int c0 = cbase + wn + ni * 16 + quad * 4;   // global col base
        const f32x4 sqc = *(const f32x4*)(sq + c0);
        const i32x4 tc  = *(const i32x4*)(tgt + c0);
        #pragma unroll
        for (int mi = 0; mi < 4; mi++) {
            #pragma unroll
            for (int j = 0; j < 4; j++) {
                const float sqd = sqr[mi] + sqc[j] - 2.0f * acc[mi][ni][j];
                float d = sqd > 0.0f ? sqrtf(sqd) : 0.0f;
                if (rg[mi] == c0 + j) d = 0.0f;           // exact diagonal
                acc[mi][ni][j] = d;
                const bool same = (trg[mi] == tc[j]);
                apv[mi] = fmaxf(apv[mi], same ? d : -1.f);
                anv[mi] = fminf(anv[mi], same ? INF : d);
            }
        }
    }
    // combine the 4 quads holding the same rows (cols 0..15 of the 16-group)
    #pragma unroll
    for (int mi = 0; mi < 4; mi++) {
        apv[mi] = fmaxf(apv[mi], __shfl_xor(apv[mi], 16));
        apv[mi] = fmaxf(apv[mi], __shfl_xor(apv[mi], 32));
        anv[mi] = fminf(anv[mi], __shfl_xor(anv[mi], 16));
        anv[mi] = fminf(anv[mi], __shfl_xor(anv[mi], 32));
    }

    // ---- C tile -> global in two 64-row halves through 32KB LDS ----
    const int rc = t & 31;                 // fixed 16B col-chunk
    const int w  = t >> 5;                 // row subset selector 0..7
    #pragma unroll
    for (int h = 0; h < 2; h++) {
        if (wm == h * 64) {                // the 2 waves owning rows of half h
            #pragma unroll
            for (int mi = 0; mi < 4; mi++) {
                const int rl = mi * 16 + l15;              // local row 0..63
                const int sw = (rl & 7) << 4;
                #pragma unroll
                for (int ni = 0; ni < 4; ni++) {
                    const int cb = (wn + ni * 16 + quad * 4) << 2;  // col byte
                    *(f32x4*)(lds + rl * 512 + (cb ^ sw)) = acc[mi][ni];
                }
            }
        }
        BAR_LDS();
        #pragma unroll
        for (int it = 0; it < 8; it++) {
            const int r = it * 8 + w;      // local row 0..63
            const f32x4 d4 = *(const f32x4*)(
                lds + r * 512 + ((rc << 4) ^ ((r & 7) << 4)));
            const int rowg = rbase + h * 64 + r;
            store_row_shifted(dist + (size_t)rowg * NROWS + cbase, d4, rc);
        }
        BAR_LDS();
    }

    // ---- combine the two col-half waves via 1KB LDS, plain-store partials --
    float* apL = (float*)lds;              // LDS free after final barrier
    float* anL = apL + 128;
    if (wn == 64 && quad == 0) {
        #pragma unroll
        for (int mi = 0; mi < 4; mi++) {
            const int lr = wm + mi * 16 + l15;
            apL[lr] = apv[mi];
            anL[lr] = anv[mi];
        }
    }
    BAR_LDS();
    if (wn == 0 && quad == 0) {
        #pragma unroll
        for (int mi = 0; mi < 4; mi++) {
            const int lr = wm + mi * 16 + l15;
            app[(size_t)bn * NROWS + rbase + lr] = fmaxf(apv[mi], apL[lr]);
            anp[(size_t)bn * NROWS + rbase + lr] = fminf(anv[mi], anL[lr]);
        }
    }
}

// fold 64 per-block-column partials per row, accumulate the loss.
// grid 32 x 256 (one thread per row); 32 atomicAdds total (tolerance 0.125).
__global__ __launch_bounds__(256) void reduce_kernel(
    const float* __restrict__ app, const float* __restrict__ anp,
    float* __restrict__ out)
{
    __shared__ float red[4];
    const int r = blockIdx.x * 256 + threadIdx.x;
    float ap = -1.0f, an = __int_as_float(0x7f800000);
    #pragma unroll 8
    for (int b = 0; b < 64; b++) {
        ap = fmaxf(ap, app[(size_t)b * NROWS + r]);
        an = fminf(an, anp[(size_t)b * NROWS + r]);
    }
    float v = ap - an + MARGIN;
    float s = v > 0.0f ? v : 0.0f;
    #pragma unroll
    for (int off = 32; off; off >>= 1) s += __shfl_xor(s, off);
    if ((threadIdx.x & 63) == 0) red[threadIdx.x >> 6] = s;
    __syncthreads();
    if (threadIdx.x == 0)
        atomicAdd(out, (red[0] + red[1] + red[2] + red[3]) * (1.0f / NROWS));
}

extern "C" void kernel_launch(void* const* d_in, const int* in_sizes, int n_in,
                              void* d_out, int out_size, void* d_ws, size_t ws_size,
                              hipStream_t stream)
{
    const float* X   = (const float*)d_in[0];
    const int*   tgt = (const int*)d_in[1];
    float*       out = (float*)d_out;

    // ws layout: Xb bf16 8192x128 (2MB) | sq (32KB) | app (2MB) | anp (2MB)
    unsigned short* Xb = (unsigned short*)d_ws;
    float* sq  = (float*)((char*)d_ws + (size_t)NROWS * DIMK * 2);
    float* app = sq + NROWS;
    float* anp = app + (size_t)64 * NROWS;

    prep_kernel<<<(NROWS * 64) / 256, 256, 0, stream>>>(X, Xb, sq, out);

    dim3 grid(64, 64);   // x = bm (fast): bn-seam neighbors share an XCD
    dist_kernel<<<grid, 256, 0, stream>>>(Xb, sq, tgt, out + 1, app, anp);

    reduce_kernel<<<NROWS / 256, 256, 0, stream>>>(app, anp, out);
}